// Round 1
// baseline (594.106 us; speedup 1.0000x reference)
//
#include <hip/hip_runtime.h>

#define POOL 14
#define CH   1024
#define CV4  (CH / 4)   // 256 float4 per pixel
#define IMGW 128

__global__ __launch_bounds__(256) void roi_pool_kernel(
    const float* __restrict__ img,   // [128,128,1024]
    const int*   __restrict__ rois,  // [512,4] (x,y,w,h)
    float*       __restrict__ out)   // [512,14,14,1024]
{
    const int blk = blockIdx.x;           // roi*POOL + py
    const int roi = blk / POOL;
    const int py  = blk - roi * POOL;
    const int t   = threadIdx.x;          // 0..255 channel float4 index

    const int4 r = reinterpret_cast<const int4*>(rois)[roi];
    const int x = r.x, y = r.y, w = r.z, h = r.w;

    // Per-op IEEE rounding to match JAX's (mul, then add) semantics exactly.
    const float fx = __fdiv_rn((float)w, (float)POOL);
    const float fy = __fdiv_rn((float)h, (float)POOL);

    // y interpolation setup (uniform across the block)
    const float gy = __fadd_rn((float)y, __fmul_rn((float)py, fy));
    const int   y0 = (int)floorf(gy);
    const float wy = gy - (float)y0;      // weight uses UNCLAMPED floor
    const int ylo = y, yhi = y + h - 1;
    const int y0c = min(max(y0,     ylo), yhi);
    const int y1c = min(max(y0 + 1, ylo), yhi);

    const float4* __restrict__ row0 =
        reinterpret_cast<const float4*>(img) + (size_t)y0c * IMGW * CV4;
    const float4* __restrict__ row1 =
        reinterpret_cast<const float4*>(img) + (size_t)y1c * IMGW * CV4;

    float4* __restrict__ orow =
        reinterpret_cast<float4*>(out) + (size_t)blk * POOL * CV4;

    const float owy = 1.0f - wy;
    const int xlo = x, xhi = x + w - 1;

    #pragma unroll 2
    for (int px = 0; px < POOL; ++px) {
        const float gx = __fadd_rn((float)x, __fmul_rn((float)px, fx));
        const int   x0 = (int)floorf(gx);
        const float wx = gx - (float)x0;  // weight uses UNCLAMPED floor
        const int x0c = min(max(x0,     xlo), xhi);
        const int x1c = min(max(x0 + 1, xlo), xhi);
        const float owx = 1.0f - wx;

        const float4 v00 = row0[x0c * CV4 + t];
        const float4 v01 = row0[x1c * CV4 + t];
        const float4 v10 = row1[x0c * CV4 + t];
        const float4 v11 = row1[x1c * CV4 + t];

        float4 o;
        o.x = (v00.x * owx + v01.x * wx) * owy + (v10.x * owx + v11.x * wx) * wy;
        o.y = (v00.y * owx + v01.y * wx) * owy + (v10.y * owx + v11.y * wx) * wy;
        o.z = (v00.z * owx + v01.z * wx) * owy + (v10.z * owx + v11.z * wx) * wy;
        o.w = (v00.w * owx + v01.w * wx) * owy + (v10.w * owx + v11.w * wx) * wy;

        orow[px * CV4 + t] = o;
    }
}

extern "C" void kernel_launch(void* const* d_in, const int* in_sizes, int n_in,
                              void* d_out, int out_size, void* d_ws, size_t ws_size,
                              hipStream_t stream) {
    const float* img  = (const float*)d_in[0];
    const int*   rois = (const int*)d_in[1];
    float*       out  = (float*)d_out;

    const int num_rois = in_sizes[1] / 4;   // 512
    dim3 grid(num_rois * POOL);             // one block per (roi, py) row
    roi_pool_kernel<<<grid, 256, 0, stream>>>(img, rois, out);
}

// Round 5
// 569.310 us; speedup vs baseline: 1.0436x; 1.0436x over previous
//
#include <hip/hip_runtime.h>

#define POOL 14
#define CH   1024
#define CV4  (CH / 4)   // 256 float4 per pixel
#define IMGW 128
#define NXCD 8

typedef float f32x4 __attribute__((ext_vector_type(4)));  // clang-native vec4

__global__ __launch_bounds__(256) void roi_pool_kernel(
    const float* __restrict__ img,   // [128,128,1024]
    const int*   __restrict__ rois,  // [512,4] (x,y,w,h)
    float*       __restrict__ out,   // [512,14,14,1024]
    int nwg)                         // total workgroups (512*14), multiple of 8
{
    // Bijective XCD-chunked swizzle: physical dispatch p lands on XCD p%8;
    // give XCD k the contiguous logical range [k*nwg/8, (k+1)*nwg/8) so all
    // 14 row-blocks of a roi (and ~64 consecutive rois) share one L2.
    const int per_xcd = nwg / NXCD;                       // 896
    const int p   = blockIdx.x;
    const int blk = (p % NXCD) * per_xcd + p / NXCD;      // logical roi*POOL+py

    const int roi = blk / POOL;
    const int py  = blk - roi * POOL;
    const int t   = threadIdx.x;          // 0..255 channel float4 index

    const int4 r = reinterpret_cast<const int4*>(rois)[roi];
    const int x = r.x, y = r.y, w = r.z, h = r.w;

    // Per-op IEEE rounding to match JAX's (mul, then add) semantics exactly.
    const float fx = __fdiv_rn((float)w, (float)POOL);
    const float fy = __fdiv_rn((float)h, (float)POOL);

    // y interpolation setup (uniform across the block)
    const float gy = __fadd_rn((float)y, __fmul_rn((float)py, fy));
    const int   y0 = (int)floorf(gy);
    const float wy = gy - (float)y0;      // weight uses UNCLAMPED floor
    const int ylo = y, yhi = y + h - 1;
    const int y0c = min(max(y0,     ylo), yhi);
    const int y1c = min(max(y0 + 1, ylo), yhi);

    const f32x4* __restrict__ row0 =
        reinterpret_cast<const f32x4*>(img) + (size_t)y0c * IMGW * CV4;
    const f32x4* __restrict__ row1 =
        reinterpret_cast<const f32x4*>(img) + (size_t)y1c * IMGW * CV4;

    f32x4* __restrict__ orow =
        reinterpret_cast<f32x4*>(out) + (size_t)blk * POOL * CV4;

    const float owy = 1.0f - wy;
    const int xlo = x, xhi = x + w - 1;

    #pragma unroll 2
    for (int px = 0; px < POOL; ++px) {
        const float gx = __fadd_rn((float)x, __fmul_rn((float)px, fx));
        const int   x0 = (int)floorf(gx);
        const float wx = gx - (float)x0;  // weight uses UNCLAMPED floor
        const int x0c = min(max(x0,     xlo), xhi);
        const int x1c = min(max(x0 + 1, xlo), xhi);
        const float owx = 1.0f - wx;

        const f32x4 v00 = row0[x0c * CV4 + t];
        const f32x4 v01 = row0[x1c * CV4 + t];
        const f32x4 v10 = row1[x0c * CV4 + t];
        const f32x4 v11 = row1[x1c * CV4 + t];

        const f32x4 o = (v00 * owx + v01 * wx) * owy
                      + (v10 * owx + v11 * wx) * wy;

        // Streaming store: output is never re-read — keep L2 for image reuse.
        __builtin_nontemporal_store(o, &orow[px * CV4 + t]);
    }
}

extern "C" void kernel_launch(void* const* d_in, const int* in_sizes, int n_in,
                              void* d_out, int out_size, void* d_ws, size_t ws_size,
                              hipStream_t stream) {
    const float* img  = (const float*)d_in[0];
    const int*   rois = (const int*)d_in[1];
    float*       out  = (float*)d_out;

    const int num_rois = in_sizes[1] / 4;   // 512
    const int nwg = num_rois * POOL;        // 7168, multiple of 8
    roi_pool_kernel<<<dim3(nwg), 256, 0, stream>>>(img, rois, out, nwg);
}